// Round 12
// baseline (968.192 us; speedup 1.0000x reference)
//
#include <hip/hip_runtime.h>

#define CH   2048
#define COLS 128          // N*H = 4*32
#define WDIM 48
#define SL   (COLS*CH)    // 262144 elems per w-slice
#define NWG  256
#define TPB  512

using f32x4  = __attribute__((ext_vector_type(4))) float;
using bf16x8 = __attribute__((ext_vector_type(8))) short;

__device__ __forceinline__ short f2bf(float f) {
    union { float f; unsigned u; } v; v.f = f;
    unsigned u = v.u;
    u += 0x7fffu + ((u >> 16) & 1u);   // round-to-nearest-even
    return (short)(u >> 16);
}

// Wc bf16 from conv_w fp32 (C,C,1,9) taking [:,:,0,4]
__global__ __launch_bounds__(256) void prep_w(const float* __restrict__ cw,
                                              short* __restrict__ wcb) {
    int idx = blockIdx.x * 256 + threadIdx.x;          // o*2048 + c
    wcb[idx] = f2bf(cw[(size_t)idx * 9 + 4]);
}

// feature (N,C,H,W) -> x_t[w][col][c], col = n*32 + h
__global__ __launch_bounds__(256) void prep_x(const float* __restrict__ feat,
                                              float* __restrict__ xt) {
    int b = blockIdx.x;
    int col = b >> 5;            // 0..127
    int ct  = b & 31;            // c-tile (64 channels)
    int n = col >> 5, h = col & 31;
    int c0 = ct * 64;
    __shared__ float tile[64][49];
    int t = threadIdx.x;
    const float* base = feat + (((size_t)n * CH + c0) * 32 + h) * WDIM;
    #pragma unroll
    for (int it = 0; it < 3; ++it) {
        int id = it * 256 + t;             // 0..767
        int row = id / 12, w4 = id % 12;
        float4 v = *reinterpret_cast<const float4*>(base + (size_t)row * 1536 + w4 * 4);
        tile[row][w4*4+0] = v.x; tile[row][w4*4+1] = v.y;
        tile[row][w4*4+2] = v.z; tile[row][w4*4+3] = v.w;
    }
    __syncthreads();
    int c = t & 63, wq = t >> 6;
    #pragma unroll
    for (int it = 0; it < 12; ++it) {
        int w = it * 4 + wq;
        xt[((size_t)w * COLS + col) * CH + c0 + c] = tile[c][w];
    }
}

__global__ __launch_bounds__(256) void init0_k(const float* __restrict__ x0,
                                               float* __restrict__ fl0,
                                               short* __restrict__ fb0) {
    int i = blockIdx.x * 256 + threadIdx.x;
    float v = x0[i];
    fl0[i] = v;
    fb0[i] = f2bf(v);
}

// Persistent kernel: 8 self-contained groups of 32 WGs (R5 geometry,
// M=64 x N=16 per WG, A panel in 128 regs/thread, 8-wave K-split).
// R12 deltas vs R5 (only two):
//  (1) per-wave publish flag: wave u (stores cols 2u,2u+1) drains its OWN
//      publish and posts its OWN flag -> third barrier removed.
//  (2) flag posted after vmcnt(0) that covers ONLY the publish store; the
//      fp32 HBM stores (fl32/outt) are issued AFTER the flag (same-thread
//      reuse only), cutting the ~1us HBM-ack wait from the critical path.
__global__ __launch_bounds__(TPB, 1) void persist_k(
        const short* __restrict__ wcb, const float* __restrict__ xt,
        short* __restrict__ flbf, short* __restrict__ bwdb,
        float* __restrict__ fl32, float* __restrict__ outt,
        const float* __restrict__ bias, const float* __restrict__ pa,
        unsigned* __restrict__ flags, int byp)
{
    __shared__ float red[8 * 16 * 65];     // 33.3 KB padded K-split reduce
    __shared__ short sst[16 * 68];         // 2.2 KB  publish transpose

    int wg = blockIdx.x;
    int grp = wg & 7;                      // 16-col chain group (XCD under RR)
    int mg  = wg >> 3;                     // 0..31 M-tile
    int n0 = grp * 16, m0 = mg * 64;
    int t = threadIdx.x;
    int wv = t >> 6, l = t & 63;
    int lc = l & 15, lg = l >> 4;

    // A panel in regs: row = m0+rb*16+lc, k = wv*256+ks*32+8*lg (+j)
    bf16x8 aR[4][8];
    {
        const short* ab = wcb + (size_t)(m0 + lc) * CH + wv * 256 + 8 * lg;
        #pragma unroll
        for (int rb = 0; rb < 4; ++rb)
            #pragma unroll
            for (int ks = 0; ks < 8; ++ks)
                aR[rb][ks] = *reinterpret_cast<const bf16x8*>(ab + (size_t)rb * 16 * CH + ks * 32);
    }

    // Epilogue constants (C/D 16x16: col=lane&15, row=(lane>>4)*4+reg; slot wv)
    int rb0 = wv >> 2, reg = wv & 3;
    int row0 = rb0 * 16 + lg * 4 + reg;    // second output at row0+32
    int o0 = m0 + row0, o1 = o0 + 32;
    size_t off0 = (size_t)(n0 + lc) * CH + o0;
    size_t off1 = off0 + 32;
    float b0 = bias[o0], b1 = bias[o1];
    float aP = *pa;
    size_t soff = (((size_t)(n0 + (t >> 5)) * CH + m0) >> 1) + (t & 31);  // int idx
    size_t boffs = (size_t)(n0 + lc) * CH + wv * 256 + 8 * lg;

    unsigned* gf = flags + grp * 256;      // 32 WGs x 8 wave-flags per group
    unsigned* myflag = gf + mg * 8 + wv;

    // Single poll per phase: all 256 wave-flags of the group >= val.
    // Lane ll reads u64s ll and 64+ll (4 flags) -> whole group in one round.
    auto poll = [&](unsigned val) {
        const unsigned long long* fp =
            reinterpret_cast<const unsigned long long*>(gf);
        int guard = 0;
        for (;;) {
            unsigned long long u0 = __hip_atomic_load(fp + l, __ATOMIC_RELAXED,
                                                      __HIP_MEMORY_SCOPE_AGENT);
            unsigned long long u1 = __hip_atomic_load(fp + 64 + l, __ATOMIC_RELAXED,
                                                      __HIP_MEMORY_SCOPE_AGENT);
            int ok = ((unsigned)u0 >= val) & ((unsigned)(u0 >> 32) >= val)
                   & ((unsigned)u1 >= val) & ((unsigned)(u1 >> 32) >= val);
            if (__all(ok)) break;
            __builtin_amdgcn_s_sleep(1);
            if (++guard > (1 << 20)) break;          // fail visibly, never hang
        }
        __builtin_amdgcn_sched_barrier(0);
    };

    float v0 = 0.f, v1 = 0.f;

    auto phase = [&](const short* src, unsigned val, const float* resp,
                     float* flw, float* outw, short* pubw, unsigned postval,
                     bool bypass) {
        float r0 = resp[off0], r1 = resp[off1];      // issue residual early
        if (val) poll(val);
        f32x4 acc[4] = {};
        const short* bp = src + boffs;
        if (!bypass) {
            bf16x8 bq[8];
            #pragma unroll
            for (int ks = 0; ks < 8; ++ks)
                bq[ks] = *reinterpret_cast<const bf16x8*>(bp + ks * 32);
            #pragma unroll
            for (int ks = 0; ks < 8; ++ks)
                #pragma unroll
                for (int rb = 0; rb < 4; ++rb)
                    acc[rb] = __builtin_amdgcn_mfma_f32_16x16x32_bf16(
                                  aR[rb][ks], bq[ks], acc[rb], 0, 0, 0);
        } else {                                     // reused addr: L2-bypass loads
            #pragma unroll
            for (int ks = 0; ks < 8; ++ks) {
                union { int i4[4]; bf16x8 v; } u;
                const int* ip = reinterpret_cast<const int*>(bp + ks * 32);
                #pragma unroll
                for (int q2 = 0; q2 < 4; ++q2)
                    u.i4[q2] = __hip_atomic_load(const_cast<int*>(ip) + q2,
                                 __ATOMIC_RELAXED, __HIP_MEMORY_SCOPE_AGENT);
                #pragma unroll
                for (int rb = 0; rb < 4; ++rb)
                    acc[rb] = __builtin_amdgcn_mfma_f32_16x16x32_bf16(
                                  aR[rb][ks], u.v, acc[rb], 0, 0, 0);
            }
        }
        #pragma unroll
        for (int rb = 0; rb < 4; ++rb)
            #pragma unroll
            for (int rg = 0; rg < 4; ++rg)
                red[wv * 1040 + (rb * 4 + rg) * 65 + l] = acc[rb][rg];
        __syncthreads();                             // B1
        float s0 = 0.f, s1 = 0.f;
        #pragma unroll
        for (int w2 = 0; w2 < 8; ++w2) {
            s0 += red[w2 * 1040 + wv * 65 + l];
            s1 += red[w2 * 1040 + (wv + 8) * 65 + l];
        }
        v0 = s0 + b0; v0 = (v0 >= 0.f) ? v0 : aP * v0; v0 += r0;
        v1 = s1 + b1; v1 = (v1 >= 0.f) ? v1 : aP * v1; v1 += r1;
        sst[lc * 68 + row0]      = f2bf(v0);
        sst[lc * 68 + row0 + 32] = f2bf(v1);
        __syncthreads();                             // B2 (also red reuse guard)
        if (pubw) {
            // wave u stores cols n0+2u, n0+2u+1 -> own drain, own flag
            int sv = reinterpret_cast<const int*>(sst)[(t >> 5) * 34 + (t & 31)];
            __hip_atomic_store(reinterpret_cast<int*>(pubw) + soff, sv,
                               __ATOMIC_RELAXED, __HIP_MEMORY_SCOPE_AGENT);
            asm volatile("s_waitcnt vmcnt(0)" ::: "memory");   // publish ack only
            if (l == 0)
                __hip_atomic_store(myflag, postval, __ATOMIC_RELAXED,
                                   __HIP_MEMORY_SCOPE_AGENT);
        }
        // HBM stores AFTER the flag: read later only by the same thread.
        if (flw)  { flw[off0] = v0;  flw[off1] = v1; }
        if (outw) { outw[off0] = v0; outw[off1] = v1; }
    };

    // ---- forward: fl[w] = prelu(Wc@fl[w-1]+b) + x[w] ----
    for (int w = 1; w <= 47; ++w)
        phase(flbf + (size_t)(w - 1) * SL, (unsigned)(w - 1),
              xt + (size_t)w * SL, fl32 + (size_t)w * SL, nullptr,
              flbf + (size_t)w * SL, (unsigned)w, false);

    // out[47] = fl[47] (own tile, from registers)
    outt[(size_t)47 * SL + off0] = v0;
    outt[(size_t)47 * SL + off1] = v1;

    // ---- backward: out[i] = prelu(Wc@state+b) + fl[i] ----
    for (int i = 46; i >= 0; --i) {
        const short* src = (i == 46) ? flbf + (size_t)47 * SL
                                     : bwdb + (size_t)(byp ? ((i + 1) & 1) : (i + 1)) * SL;
        unsigned pvw = (i == 46) ? 47u : (unsigned)(93 - i);
        bool byl = byp && (i < 45);
        short* pub = (i > 0) ? bwdb + (size_t)(byp ? (i & 1) : i) * SL : nullptr;
        phase(src, pvw, fl32 + (size_t)i * SL, nullptr,
              outt + (size_t)i * SL, pub, (unsigned)(94 - i), byl);
    }
}

// out_t[w][col][c] -> dout (N,C,H,W)
__global__ __launch_bounds__(256) void fin_t(const float* __restrict__ ot,
                                             float* __restrict__ dout) {
    int b = blockIdx.x;
    int col = b >> 5, ct = b & 31;
    int n = col >> 5, h = col & 31;
    int c0 = ct * 64;
    __shared__ float tile[48][65];
    int t = threadIdx.x;
    int c = t & 63, wq = t >> 6;
    #pragma unroll
    for (int it = 0; it < 12; ++it) {
        int w = it * 4 + wq;
        tile[w][c] = ot[((size_t)w * COLS + col) * CH + c0 + c];
    }
    __syncthreads();
    float* base = dout + (((size_t)n * CH + c0) * 32 + h) * WDIM;
    #pragma unroll
    for (int it = 0; it < 3; ++it) {
        int id = it * 256 + t;
        int row = id / 12, w4 = id % 12;
        float4 v;
        v.x = tile[w4*4+0][row]; v.y = tile[w4*4+1][row];
        v.z = tile[w4*4+2][row]; v.w = tile[w4*4+3][row];
        *reinterpret_cast<float4*>(base + (size_t)row * 1536 + w4 * 4) = v;
    }
}

extern "C" void kernel_launch(void* const* d_in, const int* in_sizes, int n_in,
                              void* d_out, int out_size, void* d_ws, size_t ws_size,
                              hipStream_t stream) {
    const float* feat = (const float*)d_in[0];
    const float* cw   = (const float*)d_in[1];
    const float* bias = (const float*)d_in[2];
    const float* pa   = (const float*)d_in[3];

    float* fl32 = (float*)d_out;                 // 48 fp32 fl slices live in d_out

    char* ws = (char*)d_ws;
    short* wcb  = (short*)(ws);                  // 8 MB    bf16 Wc
    float* xt   = (float*)(ws + 8388608);        // 48 MB   x_t (reused as out_t)
    short* flbf = (short*)(ws + 58720256);       // 24 MB   bf16 forward states (48)
    unsigned* flags = (unsigned*)(ws + 83886080);// 8 KB    per-wave step flags
    short* bwdb = (short*)(ws + 83894272);       // 23.5 MB backward states (47)
    float* outt = xt;

    const size_t needed_full = 83894272ull + 47ull * SL * 2;
    int byp = (ws_size < needed_full) ? 1 : 0;

    hipMemsetAsync(flags, 0, 8192, stream);
    prep_w<<<16384, 256, 0, stream>>>(cw, wcb);
    prep_x<<<4096, 256, 0, stream>>>(feat, xt);
    init0_k<<<1024, 256, 0, stream>>>(xt, fl32, flbf);   // fl[0] = x[0]

    persist_k<<<NWG, TPB, 0, stream>>>(wcb, xt, flbf, bwdb, fl32, outt,
                                       bias, pa, flags, byp);

    fin_t<<<4096, 256, 0, stream>>>(outt, (float*)d_out);
}

// Round 13
// 441.962 us; speedup vs baseline: 2.1907x; 2.1907x over previous
//
#include <hip/hip_runtime.h>

#define CH   2048
#define COLS 128          // N*H = 4*32
#define WDIM 48
#define SL   (COLS*CH)    // 262144 elems per w-slice
#define NWG  256
#define TPB  512

using f32x4  = __attribute__((ext_vector_type(4))) float;
using bf16x8 = __attribute__((ext_vector_type(8))) short;

__device__ __forceinline__ short f2bf(float f) {
    union { float f; unsigned u; } v; v.f = f;
    unsigned u = v.u;
    u += 0x7fffu + ((u >> 16) & 1u);   // round-to-nearest-even
    return (short)(u >> 16);
}

// Wc bf16 from conv_w fp32 (C,C,1,9) taking [:,:,0,4]
__global__ __launch_bounds__(256) void prep_w(const float* __restrict__ cw,
                                              short* __restrict__ wcb) {
    int idx = blockIdx.x * 256 + threadIdx.x;          // o*2048 + c
    wcb[idx] = f2bf(cw[(size_t)idx * 9 + 4]);
}

// feature (N,C,H,W) -> x_t[w][col][c]; also emits fl[0]=x[0] (fp32+bf16)
__global__ __launch_bounds__(256) void prep_x(const float* __restrict__ feat,
                                              float* __restrict__ xt,
                                              float* __restrict__ fl0,
                                              short* __restrict__ fb0) {
    int b = blockIdx.x;
    int col = b >> 5;            // 0..127
    int ct  = b & 31;            // c-tile (64 channels)
    int n = col >> 5, h = col & 31;
    int c0 = ct * 64;
    __shared__ float tile[64][49];
    int t = threadIdx.x;
    const float* base = feat + (((size_t)n * CH + c0) * 32 + h) * WDIM;
    #pragma unroll
    for (int it = 0; it < 3; ++it) {
        int id = it * 256 + t;             // 0..767
        int row = id / 12, w4 = id % 12;
        float4 v = *reinterpret_cast<const float4*>(base + (size_t)row * 1536 + w4 * 4);
        tile[row][w4*4+0] = v.x; tile[row][w4*4+1] = v.y;
        tile[row][w4*4+2] = v.z; tile[row][w4*4+3] = v.w;
    }
    __syncthreads();
    int c = t & 63, wq = t >> 6;
    #pragma unroll
    for (int it = 0; it < 12; ++it) {
        int w = it * 4 + wq;
        float vv = tile[c][w];
        xt[((size_t)w * COLS + col) * CH + c0 + c] = vv;
        if (w == 0) {
            fl0[(size_t)col * CH + c0 + c] = vv;
            fb0[(size_t)col * CH + c0 + c] = f2bf(vv);
        }
    }
}

// Persistent kernel: 8 self-contained groups of 32 WGs (R5 geometry,
// M=64 x N=16 per WG, A panel in 128 regs/thread, 8-wave K-split).
// R13 deltas vs R5 (latency surgery, same sync topology):
//  (1) arrival = t0 STORE to flags[mg] (32 words) - no fetch_add serialization
//  (2) raw s_barrier + hand-placed lgkmcnt(0)/vmcnt(0): B3's drain covers only
//      the 4-B publish ack; fp32 HBM stores issued AFTER the flag
//  (3) one-phase 33KB reduce (R11/R12-proven mapping): 3 barriers not 5
__global__ __launch_bounds__(TPB, 1) void persist_k(
        const short* __restrict__ wcb, const float* __restrict__ xt,
        short* __restrict__ flbf, short* __restrict__ bwdb,
        float* __restrict__ fl32, float* __restrict__ outt,
        const float* __restrict__ bias, const float* __restrict__ pa,
        unsigned* __restrict__ flags, int byp)
{
    __shared__ float red[8 * 16 * 65];     // 33.3 KB padded K-split reduce
    __shared__ short sst[16 * 68];         // 2.2 KB  publish transpose

    int wg = blockIdx.x;
    int grp = wg & 7;                      // 16-col chain group (XCD under RR)
    int mg  = wg >> 3;                     // 0..31 M-tile
    int n0 = grp * 16, m0 = mg * 64;
    int t = threadIdx.x;
    int wv = t >> 6, l = t & 63;
    int lc = l & 15, lg = l >> 4;

    // A panel in regs: row = m0+rb*16+lc, k = wv*256+ks*32+8*lg (+j)
    bf16x8 aR[4][8];
    {
        const short* ab = wcb + (size_t)(m0 + lc) * CH + wv * 256 + 8 * lg;
        #pragma unroll
        for (int rb = 0; rb < 4; ++rb)
            #pragma unroll
            for (int ks = 0; ks < 8; ++ks)
                aR[rb][ks] = *reinterpret_cast<const bf16x8*>(ab + (size_t)rb * 16 * CH + ks * 32);
    }

    // Epilogue constants (C/D 16x16: col=lane&15, row=(lane>>4)*4+reg; slot wv)
    int rb0 = wv >> 2, reg = wv & 3;
    int row0 = rb0 * 16 + lg * 4 + reg;    // second output at row0+32
    int o0 = m0 + row0, o1 = o0 + 32;
    size_t off0 = (size_t)(n0 + lc) * CH + o0;
    size_t off1 = off0 + 32;
    float b0 = bias[o0], b1 = bias[o1];
    float aP = *pa;
    size_t soff = (((size_t)(n0 + (t >> 5)) * CH + m0) >> 1) + (t & 31);  // int idx
    size_t boffs = (size_t)(n0 + lc) * CH + wv * 256 + 8 * lg;

    unsigned* gf = flags + grp * 32;       // 32 per-WG flags per group (2 lines)
    unsigned* myflag = gf + mg;

    auto poll = [&](unsigned val) {
        const unsigned* f = gf + (l & 31);
        int guard = 0;
        for (;;) {
            unsigned v = __hip_atomic_load(f, __ATOMIC_RELAXED, __HIP_MEMORY_SCOPE_AGENT);
            if (__all((int)(v >= val))) break;
            __builtin_amdgcn_s_sleep(1);
            if (++guard > (1 << 20)) break;          // fail visibly, never hang
        }
        __builtin_amdgcn_sched_barrier(0);
    };

    float v0 = 0.f, v1 = 0.f;

    auto phase = [&](const short* src, unsigned val, const float* resp,
                     float* flw, float* outw, short* pubw, unsigned postval,
                     bool bypass) {
        float r0 = resp[off0], r1 = resp[off1];      // issue residual early
        if (val) poll(val);
        f32x4 acc[4] = {};
        const short* bp = src + boffs;
        if (!bypass) {
            bf16x8 bq[8];
            #pragma unroll
            for (int ks = 0; ks < 8; ++ks)
                bq[ks] = *reinterpret_cast<const bf16x8*>(bp + ks * 32);
            #pragma unroll
            for (int ks = 0; ks < 8; ++ks)
                #pragma unroll
                for (int rb = 0; rb < 4; ++rb)
                    acc[rb] = __builtin_amdgcn_mfma_f32_16x16x32_bf16(
                                  aR[rb][ks], bq[ks], acc[rb], 0, 0, 0);
        } else {                                     // reused addr: L2-bypass loads
            #pragma unroll
            for (int ks = 0; ks < 8; ++ks) {
                union { int i4[4]; bf16x8 v; } u;
                const int* ip = reinterpret_cast<const int*>(bp + ks * 32);
                #pragma unroll
                for (int q2 = 0; q2 < 4; ++q2)
                    u.i4[q2] = __hip_atomic_load(const_cast<int*>(ip) + q2,
                                 __ATOMIC_RELAXED, __HIP_MEMORY_SCOPE_AGENT);
                #pragma unroll
                for (int rb = 0; rb < 4; ++rb)
                    acc[rb] = __builtin_amdgcn_mfma_f32_16x16x32_bf16(
                                  aR[rb][ks], u.v, acc[rb], 0, 0, 0);
            }
        }
        #pragma unroll
        for (int rb = 0; rb < 4; ++rb)
            #pragma unroll
            for (int rg = 0; rg < 4; ++rg)
                red[wv * 1040 + (rb * 4 + rg) * 65 + l] = acc[rb][rg];
        asm volatile("s_waitcnt lgkmcnt(0)" ::: "memory");     // B1: LDS only
        __builtin_amdgcn_s_barrier();
        __builtin_amdgcn_sched_barrier(0);
        float s0 = 0.f, s1 = 0.f;
        #pragma unroll
        for (int w2 = 0; w2 < 8; ++w2) {
            s0 += red[w2 * 1040 + wv * 65 + l];
            s1 += red[w2 * 1040 + (wv + 8) * 65 + l];
        }
        v0 = s0 + b0; v0 = (v0 >= 0.f) ? v0 : aP * v0; v0 += r0;
        v1 = s1 + b1; v1 = (v1 >= 0.f) ? v1 : aP * v1; v1 += r1;
        sst[lc * 68 + row0]      = f2bf(v0);
        sst[lc * 68 + row0 + 32] = f2bf(v1);
        asm volatile("s_waitcnt lgkmcnt(0)" ::: "memory");     // B2: LDS only
        __builtin_amdgcn_s_barrier();
        __builtin_amdgcn_sched_barrier(0);
        if (pubw) {
            int sv = reinterpret_cast<const int*>(sst)[(t >> 5) * 34 + (t & 31)];
            __hip_atomic_store(reinterpret_cast<int*>(pubw) + soff, sv,
                               __ATOMIC_RELAXED, __HIP_MEMORY_SCOPE_AGENT);
            asm volatile("s_waitcnt vmcnt(0)" ::: "memory");   // publish ack only
            __builtin_amdgcn_s_barrier();                       // B3
            __builtin_amdgcn_sched_barrier(0);
            if (t == 0)
                __hip_atomic_store(myflag, postval, __ATOMIC_RELAXED,
                                   __HIP_MEMORY_SCOPE_AGENT);
        }
        // fp32 HBM stores AFTER the flag: read later only by the same thread.
        if (flw)  { flw[off0] = v0;  flw[off1] = v1; }
        if (outw) { outw[off0] = v0; outw[off1] = v1; }
    };

    // ---- forward: fl[w] = prelu(Wc@fl[w-1]+b) + x[w] ----
    for (int w = 1; w <= 47; ++w)
        phase(flbf + (size_t)(w - 1) * SL, (unsigned)(w - 1),
              xt + (size_t)w * SL, fl32 + (size_t)w * SL, nullptr,
              flbf + (size_t)w * SL, (unsigned)w, false);

    // out[47] = fl[47] (own tile, from registers)
    outt[(size_t)47 * SL + off0] = v0;
    outt[(size_t)47 * SL + off1] = v1;

    // ---- backward: out[i] = prelu(Wc@state+b) + fl[i] ----
    for (int i = 46; i >= 0; --i) {
        const short* src = (i == 46) ? flbf + (size_t)47 * SL
                                     : bwdb + (size_t)(byp ? ((i + 1) & 1) : (i + 1)) * SL;
        unsigned pvw = (i == 46) ? 47u : (unsigned)(93 - i);
        bool byl = byp && (i < 45);
        short* pub = (i > 0) ? bwdb + (size_t)(byp ? (i & 1) : i) * SL : nullptr;
        phase(src, pvw, fl32 + (size_t)i * SL, nullptr,
              outt + (size_t)i * SL, pub, (unsigned)(94 - i), byl);
    }
}

// out_t[w][col][c] -> dout (N,C,H,W)
__global__ __launch_bounds__(256) void fin_t(const float* __restrict__ ot,
                                             float* __restrict__ dout) {
    int b = blockIdx.x;
    int col = b >> 5, ct = b & 31;
    int n = col >> 5, h = col & 31;
    int c0 = ct * 64;
    __shared__ float tile[48][65];
    int t = threadIdx.x;
    int c = t & 63, wq = t >> 6;
    #pragma unroll
    for (int it = 0; it < 12; ++it) {
        int w = it * 4 + wq;
        tile[w][c] = ot[((size_t)w * COLS + col) * CH + c0 + c];
    }
    __syncthreads();
    float* base = dout + (((size_t)n * CH + c0) * 32 + h) * WDIM;
    #pragma unroll
    for (int it = 0; it < 3; ++it) {
        int id = it * 256 + t;
        int row = id / 12, w4 = id % 12;
        float4 v;
        v.x = tile[w4*4+0][row]; v.y = tile[w4*4+1][row];
        v.z = tile[w4*4+2][row]; v.w = tile[w4*4+3][row];
        *reinterpret_cast<float4*>(base + (size_t)row * 1536 + w4 * 4) = v;
    }
}

extern "C" void kernel_launch(void* const* d_in, const int* in_sizes, int n_in,
                              void* d_out, int out_size, void* d_ws, size_t ws_size,
                              hipStream_t stream) {
    const float* feat = (const float*)d_in[0];
    const float* cw   = (const float*)d_in[1];
    const float* bias = (const float*)d_in[2];
    const float* pa   = (const float*)d_in[3];

    float* fl32 = (float*)d_out;                 // 48 fp32 fl slices live in d_out

    char* ws = (char*)d_ws;
    short* wcb  = (short*)(ws);                  // 8 MB    bf16 Wc
    float* xt   = (float*)(ws + 8388608);        // 48 MB   x_t (reused as out_t)
    short* flbf = (short*)(ws + 58720256);       // 24 MB   bf16 forward states (48)
    unsigned* flags = (unsigned*)(ws + 83886080);// 1 KB    per-WG step flags
    short* bwdb = (short*)(ws + 83890176);       // 23.5 MB backward states (47)
    float* outt = xt;

    const size_t needed_full = 83890176ull + 47ull * SL * 2;
    int byp = (ws_size < needed_full) ? 1 : 0;

    hipMemsetAsync(flags, 0, 1024, stream);
    prep_w<<<16384, 256, 0, stream>>>(cw, wcb);
    prep_x<<<4096, 256, 0, stream>>>(feat, xt, fl32, flbf);  // + fl[0] init

    persist_k<<<NWG, TPB, 0, stream>>>(wcb, xt, flbf, bwdb, fl32, outt,
                                       bias, pa, flags, byp);

    fin_t<<<4096, 256, 0, stream>>>(outt, (float*)d_out);
}